// Round 1
// baseline (1986.037 us; speedup 1.0000x reference)
//
#include <hip/hip_runtime.h>
#include <cstdint>
#include <cstddef>

// ---------------- problem constants ----------------
#define NB     8
#define NLOC   5000
#define NPTS   40000      // NB*NLOC
#define DIN    26
#define DH     256
#define NBINS  50
#define BSZ    100
#define KNN    16

// ---------------- workspace layout (bytes) ----------------
// emb f64 [40000][256] : 0          .. 81,920,000   (aliased later: hth @0, z @40,960,000)
// enc f32 [40000][26]  : 81,920,000 ..  4,160,000
// bin_idx i32          : 86,080,000
// order  i32           : 86,240,000
// norm   f32           : 86,400,000
// evals  f32 [..][16]  : 86,560,000
// edst   i32 [..][16]  : 89,120,000
// xenc   f32 (y alias) : 91,680,000
// fhet   f32           : 132,640,000
// gate   f32           : 173,600,000   -> total 214,560,000
static const size_t OFF_ENC  = 81920000;
static const size_t OFF_BIN  = 86080000;
static const size_t OFF_ORD  = 86240000;
static const size_t OFF_NRM  = 86400000;
static const size_t OFF_EVAL = 86560000;
static const size_t OFF_EDST = 89120000;
static const size_t OFF_XENC = 91680000;
static const size_t OFF_FHET = 132640000;
static const size_t OFF_GATE = 173600000;
static const size_t OFF_Z    = 40960000;

__device__ __forceinline__ float selu_f(float x) {
  const float scale = 1.0507009873554805f, alpha = 1.6732632423543772f;
  return x > 0.f ? scale * x : scale * alpha * expm1f(x);
}

// ---------------- 1) enc (one-hot||props) + emb = enc @ W_emb + b (f64) ----------------
__global__ __launch_bounds__(256) void k_enc_emb(
    const float* __restrict__ X, const float* __restrict__ Wemb,
    const float* __restrict__ bemb, float* __restrict__ enc,
    double* __restrict__ emb) {
  const int r = blockIdx.x;            // 0..39999
  __shared__ float e[DIN];
  const int tid = threadIdx.x;
  if (tid < DIN) {
    float v;
    if (tid < 12) {
      int id = (int)X[(size_t)r * 15];
      v = (tid == id) ? 1.f : 0.f;
    } else {
      v = X[(size_t)r * 15 + (tid - 11)];
    }
    e[tid] = v;
    enc[(size_t)r * DIN + tid] = v;
  }
  __syncthreads();
  double acc = 0.0;
  #pragma unroll 1
  for (int c = 0; c < DIN; c++)
    acc += (double)e[c] * (double)Wemb[c * DH + tid];
  emb[(size_t)r * DH + tid] = acc + (double)bemb[tid];
}

// ---------------- 2) mul = emb @ rot[:, :25]; bin = argmax([mul,-mul]) (f64) ----------------
#define MULPTS 16
__global__ __launch_bounds__(512) void k_mul(
    const double* __restrict__ emb, const float* __restrict__ rot,
    int* __restrict__ bin_idx) {
  __shared__ double ebuf[MULPTS][258];   // pad for bank spread
  __shared__ float  rotT[25][257];
  __shared__ double mulb[MULPTS][26];
  const int tid = threadIdx.x;
  const int r0 = blockIdx.x * MULPTS;
  for (int idx = tid; idx < 25 * DH; idx += 512) {
    int d = idx / 25, j = idx - d * 25;
    rotT[j][d] = rot[d * 100 + j];
  }
  for (int idx = tid; idx < MULPTS * DH; idx += 512) {
    int p = idx >> 8, d = idx & 255;
    ebuf[p][d] = emb[(size_t)(r0 + p) * DH + d];
  }
  __syncthreads();
  if (tid < MULPTS * 25) {
    int p = tid / 25, j = tid - p * 25;
    double a = 0.0;
    #pragma unroll 4
    for (int d = 0; d < DH; d++) a += ebuf[p][d] * (double)rotT[j][d];
    mulb[p][j] = a;
  }
  __syncthreads();
  if (tid < MULPTS) {
    double best = -1e300; int bi = 0;
    #pragma unroll 1
    for (int jj = 0; jj < 2 * 25; jj++) {
      double v = (jj < 25) ? mulb[tid][jj] : -mulb[tid][jj - 25];
      if (v > best) { best = v; bi = jj; }   // strict > => first occurrence (np/jnp argmax)
    }
    bin_idx[r0 + tid] = bi;
  }
}

// ---------------- 3) stable counting sort per batch -> order (= bins_split flat) ----------------
__global__ __launch_bounds__(64) void k_sort(
    const int* __restrict__ bin_idx, int* __restrict__ order) {
  const int b = blockIdx.x;
  __shared__ int bl[NLOC];
  __shared__ int cnt[NBINS];
  __shared__ int off[NBINS];
  const int tid = threadIdx.x;
  for (int n = tid; n < NLOC; n += 64) bl[n] = bin_idx[b * NLOC + n];
  __syncthreads();
  if (tid < NBINS) {
    int c = 0;
    for (int n = 0; n < NLOC; n++) c += (bl[n] == tid);
    cnt[tid] = c;
  }
  __syncthreads();
  if (tid == 0) {
    int r = 0;
    for (int j = 0; j < NBINS; j++) { off[j] = r; r += cnt[j]; }
  }
  __syncthreads();
  if (tid < NBINS) {
    int w = off[tid];
    for (int n = 0; n < NLOC; n++)
      if (bl[n] == tid) order[b * NLOC + (w++)] = n;   // stable: ascending n
  }
}

// ---------------- 4) per-(batch,bin): pairwise d2 (f64) + top-16 + vals/deg/norm ----------------
// dyn LDS: Ab double[112][129] (key[100][101] aliases it) + na double[128] + ids int[128]
#define EDGE_SMEM (112 * 129 * 8 + 128 * 8 + 128 * 4)
__global__ __launch_bounds__(256) void k_edges(
    const double* __restrict__ emb, const int* __restrict__ order,
    float* __restrict__ evals, int* __restrict__ edst,
    float* __restrict__ normv) {
  extern __shared__ char smem[];
  double* Ab  = (double*)smem;                       // [112][129]
  double* na  = (double*)(smem + 112 * 129 * 8);     // [100]
  int*    ids = (int*)(smem + 112 * 129 * 8 + 128 * 8);
  double* key = Ab;                                  // alias [100][101]
  const int blk = blockIdx.x;                        // 0..399
  const int b = blk / NBINS, bin = blk - b * NBINS;
  const int sbase = b * NLOC + bin * BSZ;            // global sorted-position base
  const int tid = threadIdx.x;
  const int tx = tid & 15, ty = tid >> 4;            // 16x16, tile 7x7
  if (tid < BSZ) ids[tid] = order[sbase + tid];
  __syncthreads();
  double acc[7][7];
  #pragma unroll
  for (int i = 0; i < 7; i++)
    #pragma unroll
    for (int j = 0; j < 7; j++) acc[i][j] = 0.0;
  for (int h = 0; h < 2; h++) {                      // two 128-d halves
    for (int idx = tid; idx < BSZ * 128; idx += 256) {
      int i = idx >> 7, d = idx & 127;
      Ab[i * 129 + d] = emb[(size_t)(b * NLOC + ids[i]) * DH + h * 128 + d];
    }
    __syncthreads();
    if (tid < BSZ) {
      double s = 0.0;
      #pragma unroll 4
      for (int d = 0; d < 128; d++) { double v = Ab[tid * 129 + d]; s += v * v; }
      if (h == 0) na[tid] = s; else na[tid] += s;
    }
    #pragma unroll 1
    for (int kk = 0; kk < 128; kk++) {
      double a[7], bb[7];
      #pragma unroll
      for (int i = 0; i < 7; i++) a[i] = Ab[(ty * 7 + i) * 129 + kk];
      #pragma unroll
      for (int j = 0; j < 7; j++) bb[j] = Ab[(tx * 7 + j) * 129 + kk];
      #pragma unroll
      for (int i = 0; i < 7; i++)
        #pragma unroll
        for (int j = 0; j < 7; j++) acc[i][j] += a[i] * bb[j];
    }
    __syncthreads();
  }
  // key = max(na_i - 2*dot + na_j, 1e-6)  (reference op order)
  #pragma unroll
  for (int i = 0; i < 7; i++) {
    int gi = ty * 7 + i; if (gi >= BSZ) break;
    #pragma unroll
    for (int j = 0; j < 7; j++) {
      int gj = tx * 7 + j; if (gj >= BSZ) continue;
      double t = na[gi] - 2.0 * acc[i][j];
      t += na[gj];
      key[gi * 101 + gj] = (t > 1e-6) ? t : 1e-6;
    }
  }
  __syncthreads();
  // bottom-16 of key == top-16 of exp(-0.1*sqrt(key)); ties -> lower index
  if (tid < BSZ) {
    const int i = tid;
    unsigned long long m0 = 0, m1 = 0;
    double deg = 0.0;
    #pragma unroll 1
    for (int k = 0; k < KNN; k++) {
      double best = 1e300; int bj = 0;
      #pragma unroll 1
      for (int j = 0; j < BSZ; j++) {
        bool taken = (j < 64) ? ((m0 >> j) & 1ull) : ((m1 >> (j - 64)) & 1ull);
        double v = key[i * 101 + j];
        if (!taken && v < best) { best = v; bj = j; }
      }
      if (bj < 64) m0 |= 1ull << bj; else m1 |= 1ull << (bj - 64);
      double val = exp(-0.1 * sqrt(best));
      deg += val;
      evals[(size_t)(sbase + i) * KNN + k] = (float)val;
      edst [(size_t)(sbase + i) * KNN + k] = ids[bj];
    }
    normv[b * NLOC + ids[i]] = (float)(1.0 / sqrt(deg + 1e-6));
  }
}

// ---------------- 5) xenc = selu(enc @ Wenc + benc) (f32, K=26) ----------------
__global__ __launch_bounds__(256) void k_encmm(
    const float* __restrict__ enc, const float* __restrict__ W,
    const float* __restrict__ bias, float* __restrict__ out) {
  const int r = blockIdx.x;
  __shared__ float e[DIN];
  const int tid = threadIdx.x;
  if (tid < DIN) e[tid] = enc[(size_t)r * DIN + tid];
  __syncthreads();
  float acc = 0.f;
  #pragma unroll 1
  for (int c = 0; c < DIN; c++) acc += e[c] * W[c * DH + tid];
  out[(size_t)r * DH + tid] = selu_f(acc + bias[tid]);
}

// ---------------- 6) generic f32 GEMM  C = act(A@B [+bias]) ; 128x128 tile, BK=32 ----------------
// ACT: 0 none, 1 selu, 2 sigmoid
template <int ACT>
__global__ __launch_bounds__(256) void k_gemm(
    const float* __restrict__ A, const float* __restrict__ B,
    const float* __restrict__ bias, float* __restrict__ C,
    int M, int N, int K) {
  __shared__ float As[32][132];   // transposed: As[k][m]
  __shared__ float Bs[32][132];
  const int tid = threadIdx.x;
  const int tx = tid & 15, ty = tid >> 4;
  const int m0 = blockIdx.x * 128, n0 = blockIdx.y * 128;
  float acc[2][4][2][4];
  #pragma unroll
  for (int a = 0; a < 2; a++)
    #pragma unroll
    for (int i = 0; i < 4; i++)
      #pragma unroll
      for (int c = 0; c < 2; c++)
        #pragma unroll
        for (int j = 0; j < 4; j++) acc[a][i][c][j] = 0.f;
  for (int k0 = 0; k0 < K; k0 += 32) {
    #pragma unroll
    for (int rep = 0; rep < 4; rep++) {
      int idx = rep * 256 + tid;
      int ml = idx >> 3, kk = (idx & 7) * 4;
      int m = m0 + ml;
      float4 v = make_float4(0.f, 0.f, 0.f, 0.f);
      if (m < M) v = *(const float4*)&A[(size_t)m * K + k0 + kk];
      As[kk + 0][ml] = v.x; As[kk + 1][ml] = v.y;
      As[kk + 2][ml] = v.z; As[kk + 3][ml] = v.w;
    }
    #pragma unroll
    for (int rep = 0; rep < 4; rep++) {
      int idx = rep * 256 + tid;
      int kk = idx >> 5, nl = (idx & 31) * 4;
      *(float4*)&Bs[kk][nl] = *(const float4*)&B[(size_t)(k0 + kk) * N + n0 + nl];
    }
    __syncthreads();
    #pragma unroll
    for (int kk = 0; kk < 32; kk++) {
      float a[2][4], bb[2][4];
      #pragma unroll
      for (int h = 0; h < 2; h++) {
        *(float4*)a[h]  = *(const float4*)&As[kk][h * 64 + ty * 4];
        *(float4*)bb[h] = *(const float4*)&Bs[kk][h * 64 + tx * 4];
      }
      #pragma unroll
      for (int ih = 0; ih < 2; ih++)
        #pragma unroll
        for (int i = 0; i < 4; i++)
          #pragma unroll
          for (int jh = 0; jh < 2; jh++)
            #pragma unroll
            for (int j = 0; j < 4; j++) acc[ih][i][jh][j] += a[ih][i] * bb[jh][j];
    }
    __syncthreads();
  }
  #pragma unroll
  for (int ih = 0; ih < 2; ih++)
    #pragma unroll
    for (int i = 0; i < 4; i++) {
      int m = m0 + ih * 64 + ty * 4 + i;
      if (m >= M) continue;
      #pragma unroll
      for (int jh = 0; jh < 2; jh++) {
        int n = n0 + jh * 64 + tx * 4;
        float4 v;
        float* pv = (float*)&v;
        #pragma unroll
        for (int j = 0; j < 4; j++) {
          float c = acc[ih][i][jh][j];
          if (bias) c += bias[n + j];
          if (ACT == 1) c = selu_f(c);
          else if (ACT == 2) c = 1.f / (1.f + expf(-c));
          pv[j] = c;
        }
        *(float4*)&C[(size_t)m * N + n] = v;
      }
    }
}

// ---------------- 7) gather-combine: y = selu(gate*agg + (1-gate)*f_het) ----------------
__global__ __launch_bounds__(256) void k_gather(
    const float* __restrict__ hth, const float* __restrict__ fhet,
    const float* __restrict__ gate, const float* __restrict__ evals,
    const int* __restrict__ edst, const int* __restrict__ order,
    const float* __restrict__ normv, float* __restrict__ y) {
  const int s = blockIdx.x;            // global sorted position
  const int b = s / NLOC;
  __shared__ float wk[KNN];
  __shared__ int   drow[KNN];
  __shared__ int   srow_s;
  __shared__ float nsrc_s;
  const int tid = threadIdx.x;
  if (tid < KNN) {
    float v = evals[(size_t)s * KNN + tid];
    int gr = b * NLOC + edst[(size_t)s * KNN + tid];
    wk[tid] = v * normv[gr];           // val * norm[dst]  (f_hom = h*norm[dst])
    drow[tid] = gr * DH;
  } else if (tid == KNN) {
    int gr = b * NLOC + order[s];
    srow_s = gr * DH;
    nsrc_s = normv[gr];
  }
  __syncthreads();
  const int d = tid;
  float acc = 0.f;
  #pragma unroll
  for (int k = 0; k < KNN; k++) acc += wk[k] * hth[drow[k] + d];
  const int srow = srow_s;
  float g = gate[srow + d], fh = fhet[srow + d];
  y[srow + d] = selu_f(g * (nsrc_s * acc) + (1.f - g) * fh);
}

// ---------------- 8) out = z @ Wout + bout ----------------
template <int OW>
__global__ __launch_bounds__(256) void k_out(
    const float* __restrict__ Z, const float* __restrict__ W,
    const float* __restrict__ bias, float* __restrict__ out) {
  const int p0 = blockIdx.x * 32;
  __shared__ float zb[32][257];
  const int tid = threadIdx.x;
  for (int idx = tid; idx < 32 * DH; idx += 256) {
    int p = idx >> 8, d = idx & 255;
    zb[p][d] = Z[(size_t)(p0 + p) * DH + d];
  }
  __syncthreads();
  if (tid < 32 * OW) {
    int p = tid / OW, o = tid - (tid / OW) * OW;
    float acc = 0.f;
    #pragma unroll 4
    for (int d = 0; d < DH; d++) acc += zb[p][d] * W[d * OW + o];
    out[(size_t)(p0 + p) * OW + o] = acc + bias[o];
  }
}

// ---------------- host ----------------
extern "C" void kernel_launch(void* const* d_in, const int* in_sizes, int n_in,
                              void* d_out, int out_size, void* d_ws, size_t ws_size,
                              hipStream_t stream) {
  const float* X     = (const float*)d_in[0];
  const float* rot   = (const float*)d_in[1];
  const float* W_emb = (const float*)d_in[2];
  const float* b_emb = (const float*)d_in[3];
  const float* Wenc[2]  = {(const float*)d_in[4],  (const float*)d_in[14]};
  const float* benc[2]  = {(const float*)d_in[5],  (const float*)d_in[15]};
  const float* theta[2] = {(const float*)d_in[6],  (const float*)d_in[16]};
  const float* Wh[2]    = {(const float*)d_in[7],  (const float*)d_in[17]};
  const float* Wt[2]    = {(const float*)d_in[8],  (const float*)d_in[18]};
  const float* bt[2]    = {(const float*)d_in[9],  (const float*)d_in[19]};
  const float* Wdec[2]  = {(const float*)d_in[10], (const float*)d_in[20]};
  const float* bdec[2]  = {(const float*)d_in[11], (const float*)d_in[21]};
  const float* Wout[2]  = {(const float*)d_in[12], (const float*)d_in[22]};
  const float* bout[2]  = {(const float*)d_in[13], (const float*)d_in[23]};

  char* w = (char*)d_ws;
  double* emb   = (double*)(w + 0);
  float*  enc   = (float*)(w + OFF_ENC);
  int*    binid = (int*)(w + OFF_BIN);
  int*    order = (int*)(w + OFF_ORD);
  float*  normv = (float*)(w + OFF_NRM);
  float*  evals = (float*)(w + OFF_EVAL);
  int*    edst  = (int*)(w + OFF_EDST);
  float*  xenc  = (float*)(w + OFF_XENC);
  float*  fhet  = (float*)(w + OFF_FHET);
  float*  gate  = (float*)(w + OFF_GATE);
  float*  hth   = (float*)(w + 0);        // alias emb (dead after k_edges)
  float*  zbuf  = (float*)(w + OFF_Z);    // alias emb upper half
  float*  ybuf  = xenc;                    // alias xenc (dead after gate GEMM)
  float*  outp  = (float*)d_out;

  k_enc_emb<<<NPTS, 256, 0, stream>>>(X, W_emb, b_emb, enc, emb);
  k_mul<<<NPTS / MULPTS, 512, 0, stream>>>(emb, rot, binid);
  k_sort<<<NB, 64, 0, stream>>>(binid, order);
  (void)hipFuncSetAttribute(reinterpret_cast<const void*>(k_edges),
                            hipFuncAttributeMaxDynamicSharedMemorySize, EDGE_SMEM);
  k_edges<<<NB * NBINS, 256, EDGE_SMEM, stream>>>(emb, order, evals, edst, normv);

  dim3 gg((NPTS + 127) / 128, 2);
  for (int br = 0; br < 2; br++) {
    k_encmm<<<NPTS, 256, 0, stream>>>(enc, Wenc[br], benc[br], xenc);
    k_gemm<0><<<gg, 256, 0, stream>>>(xenc, theta[br], nullptr, hth,  NPTS, DH, DH);
    k_gemm<0><<<gg, 256, 0, stream>>>(xenc, Wh[br],    nullptr, fhet, NPTS, DH, DH);
    k_gemm<2><<<gg, 256, 0, stream>>>(xenc, Wt[br],    bt[br],  gate, NPTS, DH, DH);
    k_gather<<<NPTS, 256, 0, stream>>>(hth, fhet, gate, evals, edst, order, normv, ybuf);
    k_gemm<1><<<gg, 256, 0, stream>>>(ybuf, Wdec[br], bdec[br], zbuf, NPTS, DH, DH);
    if (br == 0) k_out<8><<<NPTS / 32, 256, 0, stream>>>(zbuf, Wout[0], bout[0], outp);
    else         k_out<4><<<NPTS / 32, 256, 0, stream>>>(zbuf, Wout[1], bout[1], outp + (size_t)NPTS * 8);
  }
}

// Round 2
// 1175.609 us; speedup vs baseline: 1.6894x; 1.6894x over previous
//
#include <hip/hip_runtime.h>
#include <hip/hip_bf16.h>
#include <cstdint>
#include <cstddef>

// ---------------- problem constants ----------------
#define NB     8
#define NLOC   5000
#define NPTS   40000      // NB*NLOC
#define DIN    26
#define DH     256
#define NBINS  50
#define BSZ    100
#define KNN    16

// ---------------- workspace layout (bytes), total 214,560,000 ----------------
// [0 .. 81,920,000)      emb f64 [40000][256]   (dead after k_edges; then:)
//    [0 .. 40,960,000)        hth f32
//    [40,960,000 ..)          Bhi/Blo fused bf16 [768][256], Bdhi/Bdlo [256][256]
// [81,920,000 ..)        enc f32 [40000][26]
// [86,080,000 ..)        bin_idx i32
// [86,240,000 ..)        order i32
// [86,400,000 ..)        norm f32
// [86,560,000 ..)        evals f32 [..][16]
// [89,120,000 ..)        edst i32 [..][16]
// [91,680,000 ..)        Axhi bf16 [40000][256]  (later yhi)
// [112,160,000 ..)       Axlo bf16 [40000][256]  (later ylo)
// [132,640,000 ..)       fhet f32
// [173,600,000 ..)       gate f32  (dead after gather -> z f32)
static const size_t OFF_BHI  = 40960000;
static const size_t OFF_BLO  = 41353216;
static const size_t OFF_BDHI = 41746432;
static const size_t OFF_BDLO = 41877504;
static const size_t OFF_ENC  = 81920000;
static const size_t OFF_BIN  = 86080000;
static const size_t OFF_ORD  = 86240000;
static const size_t OFF_NRM  = 86400000;
static const size_t OFF_EVAL = 86560000;
static const size_t OFF_EDST = 89120000;
static const size_t OFF_AXHI = 91680000;
static const size_t OFF_AXLO = 112160000;
static const size_t OFF_FHET = 132640000;
static const size_t OFF_GATE = 173600000;

typedef __attribute__((ext_vector_type(8))) short short8;
typedef __attribute__((ext_vector_type(4))) float f32x4;

__device__ __forceinline__ float selu_f(float x) {
  const float scale = 1.0507009873554805f, alpha = 1.6732632423543772f;
  return x > 0.f ? scale * x : scale * alpha * expm1f(x);
}

__device__ __forceinline__ void split_bf16(float v, __hip_bfloat16& h, __hip_bfloat16& l) {
  h = __float2bfloat16(v);
  l = __float2bfloat16(v - __bfloat162float(h));
}

// ---------------- 1) enc (one-hot||props) + emb = enc @ W_emb + b (f64) ----------------
__global__ __launch_bounds__(256) void k_enc_emb(
    const float* __restrict__ X, const float* __restrict__ Wemb,
    const float* __restrict__ bemb, float* __restrict__ enc,
    double* __restrict__ emb) {
  const int r = blockIdx.x;
  __shared__ float e[DIN];
  const int tid = threadIdx.x;
  if (tid < DIN) {
    float v;
    if (tid < 12) {
      int id = (int)X[(size_t)r * 15];
      v = (tid == id) ? 1.f : 0.f;
    } else {
      v = X[(size_t)r * 15 + (tid - 11)];
    }
    e[tid] = v;
    enc[(size_t)r * DIN + tid] = v;
  }
  __syncthreads();
  double acc = 0.0;
  #pragma unroll 1
  for (int c = 0; c < DIN; c++)
    acc += (double)e[c] * (double)Wemb[c * DH + tid];
  emb[(size_t)r * DH + tid] = acc + (double)bemb[tid];
}

// ---------------- 2) mul = emb @ rot[:, :25]; bin = argmax([mul,-mul]) (f64) ----------------
#define MULPTS 16
__global__ __launch_bounds__(512) void k_mul(
    const double* __restrict__ emb, const float* __restrict__ rot,
    int* __restrict__ bin_idx) {
  __shared__ double ebuf[MULPTS][258];
  __shared__ float  rotT[25][257];
  __shared__ double mulb[MULPTS][26];
  const int tid = threadIdx.x;
  const int r0 = blockIdx.x * MULPTS;
  for (int idx = tid; idx < 25 * DH; idx += 512) {
    int d = idx / 25, j = idx - d * 25;
    rotT[j][d] = rot[d * 100 + j];
  }
  for (int idx = tid; idx < MULPTS * DH; idx += 512) {
    int p = idx >> 8, d = idx & 255;
    ebuf[p][d] = emb[(size_t)(r0 + p) * DH + d];
  }
  __syncthreads();
  if (tid < MULPTS * 25) {
    int p = tid / 25, j = tid - p * 25;
    double a = 0.0;
    #pragma unroll 4
    for (int d = 0; d < DH; d++) a += ebuf[p][d] * (double)rotT[j][d];
    mulb[p][j] = a;
  }
  __syncthreads();
  if (tid < MULPTS) {
    double best = -1e300; int bi = 0;
    #pragma unroll 1
    for (int jj = 0; jj < 2 * 25; jj++) {
      double v = (jj < 25) ? mulb[tid][jj] : -mulb[tid][jj - 25];
      if (v > best) { best = v; bi = jj; }   // strict > => first occurrence
    }
    bin_idx[r0 + tid] = bi;
  }
}

// ---------------- 3) stable counting sort, parallel (per-thread chunk histograms) ----------------
#define SCH 20   // 256*20 >= 5000
__global__ __launch_bounds__(256) void k_sort(
    const int* __restrict__ bin_idx, int* __restrict__ order) {
  const int b = blockIdx.x;
  __shared__ unsigned short cnt[256][NBINS + 2];
  __shared__ int base[NBINS];
  __shared__ int bl[NLOC];
  const int tid = threadIdx.x;
  for (int j = 0; j < NBINS; j++) cnt[tid][j] = 0;
  for (int n = tid; n < NLOC; n += 256) bl[n] = bin_idx[b * NLOC + n];
  __syncthreads();
  const int s = tid * SCH;
  const int e = (s + SCH < NLOC) ? s + SCH : NLOC;
  for (int n = s; n < e; n++) cnt[tid][bl[n]]++;
  __syncthreads();
  if (tid < NBINS) {                 // column exclusive prefix over chunks
    int run = 0;
    for (int t = 0; t < 256; t++) {
      int c = cnt[t][tid];
      cnt[t][tid] = (unsigned short)run;
      run += c;
    }
    base[tid] = run;                 // per-bin totals
  }
  __syncthreads();
  if (tid == 0) {
    int r = 0;
    for (int j = 0; j < NBINS; j++) { int t = base[j]; base[j] = r; r += t; }
  }
  __syncthreads();
  for (int n = s; n < e; n++) {      // stable scatter (ascending n per thread)
    int j = bl[n];
    int pos = base[j] + cnt[tid][j];
    cnt[tid][j]++;
    order[b * NLOC + pos] = n;
  }
}

// ---------------- 4) per-(batch,bin): pairwise d2 (f64) + top-16 + vals/deg/norm ----------------
#define EDGE_SMEM (112 * 129 * 8 + 128 * 8 + 128 * 4)
__global__ __launch_bounds__(256) void k_edges(
    const double* __restrict__ emb, const int* __restrict__ order,
    float* __restrict__ evals, int* __restrict__ edst,
    float* __restrict__ normv) {
  extern __shared__ char smem[];
  double* Ab  = (double*)smem;                       // [112][129]
  double* na  = (double*)(smem + 112 * 129 * 8);
  int*    ids = (int*)(smem + 112 * 129 * 8 + 128 * 8);
  double* key = Ab;                                  // alias [100][101]
  const int blk = blockIdx.x;
  const int b = blk / NBINS, bin = blk - b * NBINS;
  const int sbase = b * NLOC + bin * BSZ;
  const int tid = threadIdx.x;
  const int tx = tid & 15, ty = tid >> 4;
  if (tid < BSZ) ids[tid] = order[sbase + tid];
  __syncthreads();
  double acc[7][7];
  #pragma unroll
  for (int i = 0; i < 7; i++)
    #pragma unroll
    for (int j = 0; j < 7; j++) acc[i][j] = 0.0;
  for (int h = 0; h < 2; h++) {
    for (int idx = tid; idx < BSZ * 128; idx += 256) {
      int i = idx >> 7, d = idx & 127;
      Ab[i * 129 + d] = emb[(size_t)(b * NLOC + ids[i]) * DH + h * 128 + d];
    }
    __syncthreads();
    if (tid < BSZ) {
      double s = 0.0;
      #pragma unroll 4
      for (int d = 0; d < 128; d++) { double v = Ab[tid * 129 + d]; s += v * v; }
      if (h == 0) na[tid] = s; else na[tid] += s;
    }
    #pragma unroll 1
    for (int kk = 0; kk < 128; kk++) {
      double a[7], bb[7];
      #pragma unroll
      for (int i = 0; i < 7; i++) a[i] = Ab[(ty * 7 + i) * 129 + kk];
      #pragma unroll
      for (int j = 0; j < 7; j++) bb[j] = Ab[(tx * 7 + j) * 129 + kk];
      #pragma unroll
      for (int i = 0; i < 7; i++)
        #pragma unroll
        for (int j = 0; j < 7; j++) acc[i][j] += a[i] * bb[j];
    }
    __syncthreads();
  }
  #pragma unroll
  for (int i = 0; i < 7; i++) {
    int gi = ty * 7 + i; if (gi >= BSZ) break;
    #pragma unroll
    for (int j = 0; j < 7; j++) {
      int gj = tx * 7 + j; if (gj >= BSZ) continue;
      double t = na[gi] - 2.0 * acc[i][j];
      t += na[gj];
      key[gi * 101 + gj] = (t > 1e-6) ? t : 1e-6;
    }
  }
  __syncthreads();
  if (tid < BSZ) {
    const int i = tid;
    unsigned long long m0 = 0, m1 = 0;
    double deg = 0.0;
    #pragma unroll 1
    for (int k = 0; k < KNN; k++) {
      double best = 1e300; int bj = 0;
      #pragma unroll 1
      for (int j = 0; j < BSZ; j++) {
        bool taken = (j < 64) ? ((m0 >> j) & 1ull) : ((m1 >> (j - 64)) & 1ull);
        double v = key[i * 101 + j];
        if (!taken && v < best) { best = v; bj = j; }
      }
      if (bj < 64) m0 |= 1ull << bj; else m1 |= 1ull << (bj - 64);
      double val = exp(-0.1 * sqrt(best));
      deg += val;
      evals[(size_t)(sbase + i) * KNN + k] = (float)val;
      edst [(size_t)(sbase + i) * KNN + k] = ids[bj];
    }
    normv[b * NLOC + ids[i]] = (float)(1.0 / sqrt(deg + 1e-6));
  }
}

// ---------------- 5) xenc = selu(enc @ Wenc + benc) -> hi/lo bf16 ----------------
__global__ __launch_bounds__(256) void k_encmm(
    const float* __restrict__ enc, const float* __restrict__ W,
    const float* __restrict__ bias, __hip_bfloat16* __restrict__ hi,
    __hip_bfloat16* __restrict__ lo) {
  const int r = blockIdx.x;
  __shared__ float e[DIN];
  const int tid = threadIdx.x;
  if (tid < DIN) e[tid] = enc[(size_t)r * DIN + tid];
  __syncthreads();
  float acc = 0.f;
  #pragma unroll 1
  for (int c = 0; c < DIN; c++) acc += e[c] * W[c * DH + tid];
  float v = selu_f(acc + bias[tid]);
  __hip_bfloat16 h, l;
  split_bf16(v, h, l);
  hi[(size_t)r * DH + tid] = h;
  lo[(size_t)r * DH + tid] = l;
}

// ---------------- 6) weight transpose + hi/lo split: out[n][k] = W[k][n] ----------------
__global__ __launch_bounds__(256) void k_cvt_w(
    const float* __restrict__ W, __hip_bfloat16* __restrict__ hi,
    __hip_bfloat16* __restrict__ lo) {
  __shared__ float t[32][33];
  const int tid = threadIdx.x, tx = tid & 31, ty = tid >> 5;
  const int k0 = blockIdx.x * 32, n0 = blockIdx.y * 32;
  #pragma unroll
  for (int r = 0; r < 4; r++)
    t[ty + r * 8][tx] = W[(size_t)(k0 + ty + r * 8) * 256 + n0 + tx];
  __syncthreads();
  #pragma unroll
  for (int r = 0; r < 4; r++) {
    int n = ty + r * 8;
    float v = t[tx][n];
    __hip_bfloat16 h, l;
    split_bf16(v, h, l);
    hi[(size_t)(n0 + n) * 256 + k0 + tx] = h;
    lo[(size_t)(n0 + n) * 256 + k0 + tx] = l;
  }
}

// ---------------- 7) MFMA GEMM, 3-pass bf16 hi/lo split ----------------
// A: [40000][256] bf16 (hi,lo), Bt: [Ntot][256] bf16 (hi,lo) transposed-K layout.
// MODE 0: Ntot=768 (theta|Wh|Wt), outputs hth/fhet/gate (gate: sigmoid + bt bias)
// MODE 1: Ntot=256 (Wdec), output z = selu(.+bdec)
template <int MODE>
__global__ __launch_bounds__(256) void k_mfma(
    const ushort* __restrict__ Ahi, const ushort* __restrict__ Alo,
    const ushort* __restrict__ Bhi, const ushort* __restrict__ Blo,
    const float* __restrict__ bias,
    float* __restrict__ O0, float* __restrict__ O1, float* __restrict__ O2) {
  __shared__ short As[128][72];
  __shared__ short Bs[128][72];
  const int tid = threadIdx.x;
  const int m0 = blockIdx.x * 128;
  const int n0 = blockIdx.y * 128;
  const int lane = tid & 63, wid = tid >> 6;
  const int wr = wid >> 1, wc = wid & 1;
  const int lm = lane & 15, lg = lane >> 4;
  f32x4 acc[4][4];
  #pragma unroll
  for (int i = 0; i < 4; i++)
    #pragma unroll
    for (int j = 0; j < 4; j++)
      #pragma unroll
      for (int r = 0; r < 4; r++) acc[i][j][r] = 0.f;

  for (int pass = 0; pass < 3; pass++) {
    const ushort* Ag = (pass == 2) ? Alo : Ahi;
    const ushort* Bg = (pass == 1) ? Blo : Bhi;
    for (int k0 = 0; k0 < 256; k0 += 64) {
      #pragma unroll
      for (int it = 0; it < 4; it++) {
        int idx = it * 256 + tid;
        int r = idx >> 3, c = (idx & 7) * 8;
        int gm = m0 + r; if (gm >= NPTS) gm = NPTS - 1;
        *(uint4*)&As[r][c] = *(const uint4*)&Ag[(size_t)gm * 256 + k0 + c];
        *(uint4*)&Bs[r][c] = *(const uint4*)&Bg[(size_t)(n0 + r) * 256 + k0 + c];
      }
      __syncthreads();
      #pragma unroll
      for (int kk = 0; kk < 2; kk++) {
        short8 aF[4], bF[4];
        const int lk = kk * 32 + lg * 8;
        #pragma unroll
        for (int mf = 0; mf < 4; mf++) aF[mf] = *(const short8*)&As[wr * 64 + mf * 16 + lm][lk];
        #pragma unroll
        for (int nf = 0; nf < 4; nf++) bF[nf] = *(const short8*)&Bs[wc * 64 + nf * 16 + lm][lk];
        #pragma unroll
        for (int mf = 0; mf < 4; mf++)
          #pragma unroll
          for (int nf = 0; nf < 4; nf++)
            acc[mf][nf] = __builtin_amdgcn_mfma_f32_16x16x32_bf16(aF[mf], bF[nf], acc[mf][nf], 0, 0, 0);
      }
      __syncthreads();
    }
  }

  // epilogue
  float* Out; int cb;
  if (MODE == 0) {
    const int seg = blockIdx.y >> 1;
    Out = (seg == 0) ? O0 : ((seg == 1) ? O1 : O2);
    cb = (blockIdx.y & 1) * 128;
  } else {
    Out = O0; cb = n0;
  }
  const bool do_gate = (MODE == 0) && (blockIdx.y >> 1) == 2;
  #pragma unroll
  for (int mf = 0; mf < 4; mf++) {
    const int gm0 = m0 + wr * 64 + mf * 16 + lg * 4;
    #pragma unroll
    for (int nf = 0; nf < 4; nf++) {
      const int gn = cb + wc * 64 + nf * 16 + lm;
      #pragma unroll
      for (int r = 0; r < 4; r++) {
        const int gm = gm0 + r;
        if (gm >= NPTS) continue;
        float c = acc[mf][nf][r];
        if (MODE == 1)      c = selu_f(c + bias[gn]);
        else if (do_gate)   c = 1.f / (1.f + expf(-(c + bias[gn])));
        Out[(size_t)gm * 256 + gn] = c;
      }
    }
  }
}

// ---------------- 8) gather-combine -> y hi/lo bf16 ----------------
__global__ __launch_bounds__(256) void k_gather(
    const float* __restrict__ hth, const float* __restrict__ fhet,
    const float* __restrict__ gate, const float* __restrict__ evals,
    const int* __restrict__ edst, const int* __restrict__ order,
    const float* __restrict__ normv, __hip_bfloat16* __restrict__ yhi,
    __hip_bfloat16* __restrict__ ylo) {
  const int s = blockIdx.x;
  const int b = s / NLOC;
  __shared__ float wk[KNN];
  __shared__ int   drow[KNN];
  __shared__ int   srow_s;
  __shared__ float nsrc_s;
  const int tid = threadIdx.x;
  if (tid < KNN) {
    float v = evals[(size_t)s * KNN + tid];
    int gr = b * NLOC + edst[(size_t)s * KNN + tid];
    wk[tid] = v * normv[gr];
    drow[tid] = gr * DH;
  } else if (tid == KNN) {
    int gr = b * NLOC + order[s];
    srow_s = gr * DH;
    nsrc_s = normv[gr];
  }
  __syncthreads();
  const int d = tid;
  float acc = 0.f;
  #pragma unroll
  for (int k = 0; k < KNN; k++) acc += wk[k] * hth[drow[k] + d];
  const int srow = srow_s;
  float g = gate[srow + d], fh = fhet[srow + d];
  float v = selu_f(g * (nsrc_s * acc) + (1.f - g) * fh);
  __hip_bfloat16 h, l;
  split_bf16(v, h, l);
  yhi[srow + d] = h;
  ylo[srow + d] = l;
}

// ---------------- 9) out = z @ Wout + bout ----------------
template <int OW>
__global__ __launch_bounds__(256) void k_out(
    const float* __restrict__ Z, const float* __restrict__ W,
    const float* __restrict__ bias, float* __restrict__ out) {
  const int p0 = blockIdx.x * 32;
  __shared__ float zb[32][257];
  const int tid = threadIdx.x;
  for (int idx = tid; idx < 32 * DH; idx += 256) {
    int p = idx >> 8, d = idx & 255;
    zb[p][d] = Z[(size_t)(p0 + p) * DH + d];
  }
  __syncthreads();
  if (tid < 32 * OW) {
    int p = tid / OW, o = tid - (tid / OW) * OW;
    float acc = 0.f;
    #pragma unroll 4
    for (int d = 0; d < DH; d++) acc += zb[p][d] * W[d * OW + o];
    out[(size_t)(p0 + p) * OW + o] = acc + bias[o];
  }
}

// ---------------- host ----------------
extern "C" void kernel_launch(void* const* d_in, const int* in_sizes, int n_in,
                              void* d_out, int out_size, void* d_ws, size_t ws_size,
                              hipStream_t stream) {
  const float* X     = (const float*)d_in[0];
  const float* rot   = (const float*)d_in[1];
  const float* W_emb = (const float*)d_in[2];
  const float* b_emb = (const float*)d_in[3];
  const float* Wenc[2]  = {(const float*)d_in[4],  (const float*)d_in[14]};
  const float* benc[2]  = {(const float*)d_in[5],  (const float*)d_in[15]};
  const float* theta[2] = {(const float*)d_in[6],  (const float*)d_in[16]};
  const float* Wh[2]    = {(const float*)d_in[7],  (const float*)d_in[17]};
  const float* Wt[2]    = {(const float*)d_in[8],  (const float*)d_in[18]};
  const float* bt[2]    = {(const float*)d_in[9],  (const float*)d_in[19]};
  const float* Wdec[2]  = {(const float*)d_in[10], (const float*)d_in[20]};
  const float* bdec[2]  = {(const float*)d_in[11], (const float*)d_in[21]};
  const float* Wout[2]  = {(const float*)d_in[12], (const float*)d_in[22]};
  const float* bout[2]  = {(const float*)d_in[13], (const float*)d_in[23]};

  char* w = (char*)d_ws;
  double* emb   = (double*)(w + 0);
  float*  hth   = (float*)(w + 0);                  // alias emb (dead after k_edges)
  __hip_bfloat16* Bhi  = (__hip_bfloat16*)(w + OFF_BHI);
  __hip_bfloat16* Blo  = (__hip_bfloat16*)(w + OFF_BLO);
  __hip_bfloat16* Bdhi = (__hip_bfloat16*)(w + OFF_BDHI);
  __hip_bfloat16* Bdlo = (__hip_bfloat16*)(w + OFF_BDLO);
  float*  enc   = (float*)(w + OFF_ENC);
  int*    binid = (int*)(w + OFF_BIN);
  int*    order = (int*)(w + OFF_ORD);
  float*  normv = (float*)(w + OFF_NRM);
  float*  evals = (float*)(w + OFF_EVAL);
  int*    edst  = (int*)(w + OFF_EDST);
  __hip_bfloat16* Axhi = (__hip_bfloat16*)(w + OFF_AXHI);  // also yhi
  __hip_bfloat16* Axlo = (__hip_bfloat16*)(w + OFF_AXLO);  // also ylo
  float*  fhet  = (float*)(w + OFF_FHET);
  float*  gate  = (float*)(w + OFF_GATE);
  float*  zbuf  = (float*)(w + OFF_GATE);           // alias gate (dead after gather)
  float*  outp  = (float*)d_out;

  k_enc_emb<<<NPTS, 256, 0, stream>>>(X, W_emb, b_emb, enc, emb);
  k_mul<<<NPTS / MULPTS, 512, 0, stream>>>(emb, rot, binid);
  k_sort<<<NB, 256, 0, stream>>>(binid, order);
  (void)hipFuncSetAttribute(reinterpret_cast<const void*>(k_edges),
                            hipFuncAttributeMaxDynamicSharedMemorySize, EDGE_SMEM);
  k_edges<<<NB * NBINS, 256, EDGE_SMEM, stream>>>(emb, order, evals, edst, normv);

  const dim3 gw(8, 8);
  const dim3 gf(313, 6), gd(313, 2);
  for (int br = 0; br < 2; br++) {
    // weight conversions (into dead emb region; after k_edges in stream order)
    k_cvt_w<<<gw, 256, 0, stream>>>(theta[br], Bhi,             Blo);
    k_cvt_w<<<gw, 256, 0, stream>>>(Wh[br],    Bhi + 256 * 256, Blo + 256 * 256);
    k_cvt_w<<<gw, 256, 0, stream>>>(Wt[br],    Bhi + 512 * 256, Blo + 512 * 256);
    k_cvt_w<<<gw, 256, 0, stream>>>(Wdec[br],  Bdhi,            Bdlo);

    k_encmm<<<NPTS, 256, 0, stream>>>(enc, Wenc[br], benc[br], Axhi, Axlo);
    k_mfma<0><<<gf, 256, 0, stream>>>((const ushort*)Axhi, (const ushort*)Axlo,
                                      (const ushort*)Bhi, (const ushort*)Blo,
                                      bt[br], hth, fhet, gate);
    k_gather<<<NPTS, 256, 0, stream>>>(hth, fhet, gate, evals, edst, order, normv,
                                       Axhi, Axlo);
    k_mfma<1><<<gd, 256, 0, stream>>>((const ushort*)Axhi, (const ushort*)Axlo,
                                      (const ushort*)Bdhi, (const ushort*)Bdlo,
                                      bdec[br], zbuf, nullptr, nullptr);
    if (br == 0) k_out<8><<<NPTS / 32, 256, 0, stream>>>(zbuf, Wout[0], bout[0], outp);
    else         k_out<4><<<NPTS / 32, 256, 0, stream>>>(zbuf, Wout[1], bout[1], outp + (size_t)NPTS * 8);
  }
}